// Round 3
// baseline (16484.398 us; speedup 1.0000x reference)
//
#include <hip/hip_runtime.h>

// Tanh RNN: B=64, S=2048, I=H=512, fp32 in/out.
// slotinit: poison all 2049 h-slots; slot0 = fp16(state).
// prep:     w_ih,w_hh -> fp16; bias = b_ih+b_hh.
// xproj:    xp16[s*64+b][h] = inputs[b][s][:].w_ih[h][:] + bias[h]  (fp16 out)
// rnn:      16 persistent WGs (4 row-groups x 4 col-slices), w_hh in VGPRs.
//           h_t lives in slot[t] (unique per step, written once). Consumers
//           poll slot[t] qwords until != POISON (fp16 NaN pattern). No
//           fences, no flags, no barriers, no re-poisoning, no vmcnt asm.

typedef _Float16 half8 __attribute__((ext_vector_type(8)));
typedef _Float16 half4 __attribute__((ext_vector_type(4)));
typedef float f32x4 __attribute__((ext_vector_type(4)));
typedef unsigned long long u64;

#define S_SZ 2048
#define OUT1_OFF 67108864ull   // S*B*H floats

// workspace offsets (bytes); total ~269.55 MB (<= round-1's proven footprint)
#define XP_OFF    0ull              // 2048*64*512*2   = 134217728
#define SLOT_OFF  134217728ull      // 2049*8192*8     = 134283264
#define WHH_OFF   268500992ull      // 524288
#define WIH_OFF   269025280ull      // 524288
#define BIAS_OFF  269549568ull      // 2048

#define POISON 0x7FFF7FFF7FFF7FFFull

__device__ __forceinline__ float fast_tanh(float x) {
    float a = exp2f(fminf(fmaxf(x * 2.8853900817779268f, -30.f), 30.f));
    return (a - 1.0f) * __builtin_amdgcn_rcpf(a + 1.0f);
}

// poison all slots; slot 0 = packed fp16 state (row-major [64][512])
__global__ void slotinit_kernel(const float* __restrict__ state, u64* __restrict__ slotq)
{
    const int gid = blockIdx.x * 256 + threadIdx.x;  // 65568 blocks -> 16785408 == 2049*8192
    if (gid < 8192) {
        union { _Float16 h[4]; u64 u; } p;
        #pragma unroll
        for (int j = 0; j < 4; ++j) p.h[j] = (_Float16)state[gid * 4 + j];
        slotq[gid] = p.u;
    } else {
        slotq[gid] = POISON;
    }
}

__global__ void prep_kernel(const float* __restrict__ wih, const float* __restrict__ whh,
                            const float* __restrict__ bih, const float* __restrict__ bhh,
                            _Float16* __restrict__ wih16, _Float16* __restrict__ whh16,
                            float* __restrict__ bias)
{
    const int i = blockIdx.x * 256 + threadIdx.x;   // 1024 blocks -> 262144
    wih16[i] = (_Float16)wih[i];
    whh16[i] = (_Float16)whh[i];
    if (i < 512) bias[i] = bih[i] + bhh[i];
}

// ---------------- input projection GEMM ----------------
// Swapped MFMA (A=w cols, B=x rows): D lane l15 = batch row, reg quad = 4
// consecutive h-cols -> packed half4 stores.
__global__ __launch_bounds__(512, 1) void xproj_kernel(
    const float* __restrict__ inputs, const _Float16* __restrict__ wih16,
    const float* __restrict__ bias, _Float16* __restrict__ xp16)
{
    __shared__ _Float16 Alds[64 * 512];  // 64 KiB, swizzled
    const int s = blockIdx.x;

    for (int idx = threadIdx.x; idx < 64 * 128; idx += 512) {
        const int row = idx >> 7, chunk = idx & 127;
        const float4 v = *reinterpret_cast<const float4*>(
            inputs + ((size_t)row * S_SZ + s) * 512 + chunk * 4);
        half4 hv;
        hv[0] = (_Float16)v.x; hv[1] = (_Float16)v.y;
        hv[2] = (_Float16)v.z; hv[3] = (_Float16)v.w;
        const int bc = (chunk * 8) ^ ((row & 7) << 4);
        *reinterpret_cast<half4*>(reinterpret_cast<char*>(Alds) + row * 1024 + bc) = hv;
    }
    __syncthreads();

    const int lane = threadIdx.x & 63, w = threadIdx.x >> 6;
    const int l15 = lane & 15, lg = lane >> 4;

    f32x4 acc[4][4];
    #pragma unroll
    for (int m = 0; m < 4; ++m)
        #pragma unroll
        for (int n = 0; n < 4; ++n)
            acc[m][n] = 0.0f;

    for (int kk = 0; kk < 16; ++kk) {
        half8 af[4], bf[4];
        #pragma unroll
        for (int m = 0; m < 4; ++m) {
            const int row = m * 16 + l15;
            const int bc = (kk * 64 + lg * 16) ^ ((row & 7) << 4);
            af[m] = *reinterpret_cast<const half8*>(
                reinterpret_cast<const char*>(Alds) + row * 1024 + bc);
        }
        #pragma unroll
        for (int n = 0; n < 4; ++n) {
            const int col = w * 64 + n * 16 + l15;
            bf[n] = *reinterpret_cast<const half8*>(wih16 + (size_t)col * 512 + kk * 32 + lg * 8);
        }
        #pragma unroll
        for (int m = 0; m < 4; ++m)
            #pragma unroll
            for (int n = 0; n < 4; ++n)
                acc[m][n] = __builtin_amdgcn_mfma_f32_16x16x32_f16(bf[n], af[m], acc[m][n], 0, 0, 0);
    }

    #pragma unroll
    for (int m = 0; m < 4; ++m) {
        const int brow = m * 16 + l15;   // batch row (D lane dim)
        #pragma unroll
        for (int n = 0; n < 4; ++n) {
            const int j0 = w * 64 + n * 16 + lg * 4;  // first of 4 h-cols (D quad dim)
            const float4 bv = *reinterpret_cast<const float4*>(bias + j0);
            half4 hv;
            hv[0] = (_Float16)(acc[m][n][0] + bv.x);
            hv[1] = (_Float16)(acc[m][n][1] + bv.y);
            hv[2] = (_Float16)(acc[m][n][2] + bv.z);
            hv[3] = (_Float16)(acc[m][n][3] + bv.w);
            *reinterpret_cast<half4*>(xp16 + ((size_t)s * 64 + brow) * 512 + j0) = hv;
        }
    }
}

// ---------------- persistent recurrence: write-once slots ----------------
__global__ __launch_bounds__(256, 1) void rnn_step_kernel(
    const _Float16* __restrict__ whh16, const _Float16* __restrict__ xp16,
    u64* __restrict__ slotq, float* __restrict__ out)
{
    const int r = blockIdx.x >> 2, c = blockIdx.x & 3;
    const int tid = threadIdx.x;
    const int lane = tid & 63, w = tid >> 6;
    const int l15 = lane & 15, lg = lane >> 4;
    const int colbase = c * 128 + w * 32;
    const int row = r * 16 + l15;                 // batch row for xp/out (D lane dim)

    // w_hh A-operand fragments: wf[n][kk] covers j = colbase+n*16+l15,
    // k = kk*32 + lg*8 .. +8
    half8 wf[2][16];
    #pragma unroll
    for (int n = 0; n < 2; ++n) {
        const _Float16* wp = whh16 + (size_t)(colbase + n * 16 + l15) * 512 + lg * 8;
        #pragma unroll
        for (int kk = 0; kk < 16; ++kk)
            wf[n][kk] = *reinterpret_cast<const half8*>(wp + kk * 32);
    }

    const int qin_off  = r * 2048 + l15 * 128 + lg * 2;              // + t*8192 + kk*8 (+0/1)
    const int qout_off = r * 2048 + l15 * 128 + (colbase >> 2) + lg; // + (t+1)*8192 (+n*4)

    // xp prefetch for t=0 (raw qwords; convert at use)
    u64 xv0, xv1;
    {
        const _Float16* xpb = xp16 + (size_t)row * 512 + colbase + lg * 4;
        xv0 = *reinterpret_cast<const u64*>(xpb);
        xv1 = *reinterpret_cast<const u64*>(xpb + 16);
    }

    long budget = 30000000L;  // anti-hang escape; never hit if correct

    #pragma unroll 1
    for (int t = 0; t < S_SZ; ++t) {
        // ---- poll-read h_t from slot t (write-once -> no ABA) ----
        u64* qin = slotq + (size_t)t * 8192 + qin_off;
        u64 q[32];
        for (;;) {
            #pragma unroll
            for (int kk = 0; kk < 16; ++kk) {
                q[2 * kk]     = __hip_atomic_load(qin + kk * 8,     __ATOMIC_RELAXED, __HIP_MEMORY_SCOPE_AGENT);
                q[2 * kk + 1] = __hip_atomic_load(qin + kk * 8 + 1, __ATOMIC_RELAXED, __HIP_MEMORY_SCOPE_AGENT);
            }
            bool ok = true;
            #pragma unroll
            for (int i = 0; i < 32; ++i) ok &= (q[i] != POISON);
            if (ok || --budget <= 0) break;
        }

        // ---- MFMA: D[j][b] += w[j][k] * h[b][k] ----
        f32x4 acc0 = 0.0f, acc1 = 0.0f;
        #pragma unroll
        for (int kk = 0; kk < 16; ++kk) {
            union { u64 u[2]; half8 h; } cvt;
            cvt.u[0] = q[2 * kk]; cvt.u[1] = q[2 * kk + 1];
            acc0 = __builtin_amdgcn_mfma_f32_16x16x32_f16(wf[0][kk], cvt.h, acc0, 0, 0, 0);
            acc1 = __builtin_amdgcn_mfma_f32_16x16x32_f16(wf[1][kk], cvt.h, acc1, 0, 0, 0);
        }

        // ---- tanh + pack ----
        union { _Float16 h[4]; u64 u; } x0c, x1c;
        x0c.u = xv0; x1c.u = xv1;
        f32x4 f0, f1;
        union { _Float16 h[4]; u64 u; } p0, p1;
        #pragma unroll
        for (int qq = 0; qq < 4; ++qq) {
            f0[qq] = fast_tanh(acc0[qq] + (float)x0c.h[qq]);
            f1[qq] = fast_tanh(acc1[qq] + (float)x1c.h[qq]);
            p0.h[qq] = (_Float16)f0[qq];
            p1.h[qq] = (_Float16)f1[qq];
        }

        // ---- publish h_{t+1} FIRST (latency-critical) ----
        u64* qout = slotq + (size_t)(t + 1) * 8192 + qout_off;
        __hip_atomic_store(qout,     p0.u, __ATOMIC_RELAXED, __HIP_MEMORY_SCOPE_AGENT);
        __hip_atomic_store(qout + 4, p1.u, __ATOMIC_RELAXED, __HIP_MEMORY_SCOPE_AGENT);

        // ---- fp32 outputs (normal stores: L2-ack keeps later vmcnt cheap) ----
        float* orow = out + ((size_t)t * 64 + row) * 512 + colbase + lg * 4;
        *reinterpret_cast<f32x4*>(orow)      = f0;
        *reinterpret_cast<f32x4*>(orow + 16) = f1;

        if (t == S_SZ - 1) {
            #pragma unroll
            for (int qq = 0; qq < 4; ++qq) {
                out[OUT1_OFF + (size_t)(colbase + lg * 4 + qq) * 64 + row] = f0[qq];
                out[OUT1_OFF + (size_t)(colbase + 16 + lg * 4 + qq) * 64 + row] = f1[qq];
            }
        }

        // ---- prefetch xp for t+1 ----
        if (t + 1 < S_SZ) {
            const _Float16* xpb = xp16 + ((size_t)(t + 1) * 64 + row) * 512 + colbase + lg * 4;
            xv0 = *reinterpret_cast<const u64*>(xpb);
            xv1 = *reinterpret_cast<const u64*>(xpb + 16);
        }
    }
}

extern "C" void kernel_launch(void* const* d_in, const int* in_sizes, int n_in,
                              void* d_out, int out_size, void* d_ws, size_t ws_size,
                              hipStream_t stream)
{
    const float* inputs = (const float*)d_in[0];
    const float* state  = (const float*)d_in[1];
    const float* w_ih   = (const float*)d_in[2];
    const float* b_ih   = (const float*)d_in[3];
    const float* w_hh   = (const float*)d_in[4];
    const float* b_hh   = (const float*)d_in[5];
    float* out = (float*)d_out;
    char* ws = (char*)d_ws;

    _Float16* xp16  = (_Float16*)(ws + XP_OFF);
    u64*      slotq = (u64*)(ws + SLOT_OFF);
    _Float16* whh16 = (_Float16*)(ws + WHH_OFF);
    _Float16* wih16 = (_Float16*)(ws + WIH_OFF);
    float*    bias  = (float*)(ws + BIAS_OFF);

    slotinit_kernel<<<65568, 256, 0, stream>>>(state, slotq);
    prep_kernel<<<1024, 256, 0, stream>>>(w_ih, w_hh, b_ih, b_hh, wih16, whh16, bias);
    xproj_kernel<<<S_SZ, 512, 0, stream>>>(inputs, wih16, bias, xp16);
    rnn_step_kernel<<<16, 256, 0, stream>>>(whh16, xp16, slotq, out);
}